// Round 10
// baseline (549.198 us; speedup 1.0000x reference)
//
#include <hip/hip_runtime.h>
#include <hip/hip_cooperative_groups.h>
#include <stdint.h>

namespace cg = cooperative_groups;

// y[t][o] = sum_i x[t][i] * ((w_pos[o][i]>0) - (w_neg[o][i]>0))
// Single COOPERATIVE kernel: per-block prep slice -> cg::grid().sync()
// -> two 256x256 GEMM tiles. M=8192, N=4096, K=4096. fp32 out.
// ws: [0,64MiB) x_bf16 ; [64MiB,96MiB) tern_bf16.
//
// R10: inner shape 16x16x32 -> 32x32x16 (m119: 2495 vs 2075-2176 TF).
// Same LDS traffic (6x1KB reads/phase/wave), same schedule skeleton,
// MFMA pipe 620 -> ~516 cy/phase. Supporting changes:
//  - slot fn f(r) = ((r>>1)^(r>>3))&3 (32-row frag reads bank-balanced;
//    old (r>>1)&3 4-way-conflicts rows {r, r+8, r+16, r+24}).
//  - f(r+16) = f(r)^2 => staging second copy global addr = (g^32)+131072.
//  - even/odd k-slice fragment bases (aO = aE ^ 32; LDS align 128).
//  - C/D layout for 32x32: col=lane&31, row=(reg&3)+8*(reg>>2)+4*(lane>>5).

#define TOKENS 8192
#define DIN    4096
#define DOUT   4096

typedef __bf16  bf16x8   __attribute__((ext_vector_type(8)));
typedef float   floatx4  __attribute__((ext_vector_type(4)));
typedef float   floatx16 __attribute__((ext_vector_type(16)));
typedef float   f32x4    __attribute__((ext_vector_type(4)));
typedef unsigned short u16x4 __attribute__((ext_vector_type(4)));

__device__ __forceinline__ void async_copy16(const void* g, void* l) {
  __builtin_amdgcn_global_load_lds(
      (const __attribute__((address_space(1))) void*)g,
      (__attribute__((address_space(3))) void*)l, 16, 0, 0);
}

__device__ __forceinline__ unsigned short f2bf_rne(float f) {
  union { float f; uint32_t u; } v; v.f = f;
  uint32_t u = v.u;
  u += 0x7fffu + ((u >> 16) & 1u);
  return (unsigned short)(u >> 16);
}

__device__ __forceinline__ unsigned short tern_bits(float p, float n) {
  bool bp = p > 0.0f, bn = n > 0.0f;
  return (unsigned short)(bp == bn ? 0u : (bp ? 0x3f80u : 0xbf80u));
}

// ---------------------------------------------------------------------------
// LDS map (per buffer b in {0,1}, base b*65536): A at +0, B at +32768;
// each tile [kc in 2][256 rows][64B row]. 64-B row = 4 chunks of 16 B;
// chunk c stored at slot c ^ f(row), f(r) = ((r>>1)^(r>>3))&3. Inverse
// applied on per-lane GLOBAL source (staging; LDS dest stays linear),
// forward applied on LDS read addresses.
//
// K-tile (BK=64) = 4 k-slices j=0..3 of K=16 (j>>1 = kc, j&1 = 32B half).
// Per wave per phase: compute one k-slice = 8 x mfma_32x32x16 (4m x 2n),
// issue next slice's 4 A + 2 B ds_read_b128 into the other reg bank.
// Phase P: [ lgkmcnt(0); vmcnt(8); issue 6 reads; 8 MFMA (setprio);
//            stage 2 global_load_lds; s_barrier ].
// Stage map (= R3/R9, verified): Ph1:b1.Ak1(T2i+1) Ph2:b0.Bk0 Ph3:b0.Ak0
//   Ph4:b0.Bk1 Ph5:b0.Ak1 (T2i+2) Ph6:b1.Bk0 Ph7:b1.Ak0 Ph8:b1.Bk1(T2i+3).
// Read-issue map: Ph1:b0.j1 Ph2:b0.j2 Ph3:b0.j3 Ph4:b1.j0 Ph5:b1.j1
//   Ph6:b1.j2 Ph7:b1.j3 Ph8:next b0.j0 (prime covers first b0.j0).
// RAW: vmcnt(8)@P-top retires stages <= P-5; every read's source stage is
// exactly at or older than that horizon (checked all 8 regions + prologue).
// WAR: each staged region's last old-content read-issue is >= 1 phase (or
// same-phase with ~500cy MFMA separation) before the stage (all checked).
// ---------------------------------------------------------------------------

#define LDS_BUF   65536u
#define LDS_B_OFF 32768u
#define LDS_KC    16384u

__global__ __launch_bounds__(512, 2) void fused_kernel(
    const float* __restrict__ x,    // [8192,4096] fp32
    const float* __restrict__ wp,   // [4096,4096] fp32
    const float* __restrict__ wn,   // [4096,4096] fp32
    unsigned short* __restrict__ xb,    // ws: bf16 x
    unsigned short* __restrict__ tern,  // ws: bf16 ternary
    float* __restrict__ C)          // [8192,4096] fp32
{
  __shared__ __align__(128) char lds[131072];

  const int tid = threadIdx.x;
  const uint32_t b = blockIdx.x;   // 0..255

  // ===== prep slice: 1/256 of cvt(x) and tern(wp,wn) =====
  {
    const f32x4* xf = (const f32x4*)x;
    u16x4* xo = (u16x4*)xb;
    uint32_t i = b * 32768u + (uint32_t)tid;
#pragma unroll 4
    for (int j = 0; j < 64; ++j, i += 512u) {
      f32x4 v = __builtin_nontemporal_load(&xf[i]);
      u16x4 o;
      o.x = f2bf_rne(v.x); o.y = f2bf_rne(v.y);
      o.z = f2bf_rne(v.z); o.w = f2bf_rne(v.w);
      xo[i] = o;
    }
    const f32x4* wpf = (const f32x4*)wp;
    const f32x4* wnf = (const f32x4*)wn;
    u16x4* to = (u16x4*)tern;
    uint32_t k = b * 16384u + (uint32_t)tid;
#pragma unroll 4
    for (int j = 0; j < 32; ++j, k += 512u) {
      f32x4 p = __builtin_nontemporal_load(&wpf[k]);
      f32x4 n = __builtin_nontemporal_load(&wnf[k]);
      u16x4 o;
      o.x = tern_bits(p.x, n.x);
      o.y = tern_bits(p.y, n.y);
      o.z = tern_bits(p.z, n.z);
      o.w = tern_bits(p.w, n.w);
      to[k] = o;
    }
  }

  // ===== supported grid-wide barrier (cooperative launch) =====
  asm volatile("s_waitcnt vmcnt(0) lgkmcnt(0)" ::: "memory");
  cg::this_grid().sync();
  __builtin_amdgcn_sched_barrier(0);

  // ===== GEMM: two tiles per block =====
  const int lane  = tid & 63;
  const int wid   = tid >> 6;
  const int waveM = wid >> 2;   // 0..1
  const int waveN = wid & 3;    // 0..3

  // Fragment constants (32x32x16): lane holds row/col r5 = lane&31,
  // k-half q = lane>>5 (8 bf16 = 16 B). Slot = ((j&1)*2 + q) ^ f(r5);
  // the (j&1)*2 term is an XOR of 32 on the byte address (bits 4-5 hold
  // only the slot field; rows are 64B-aligned, LDS base 128-aligned).
  const int r5 = lane & 31;
  const int q  = lane >> 5;
  const uint32_t fr = (((uint32_t)r5 >> 1) ^ ((uint32_t)r5 >> 3)) & 3u;
  const uint32_t ldsBase =
      (uint32_t)(uintptr_t)(__attribute__((address_space(3))) char*)lds;
  const uint32_t slotA = ((uint32_t)q ^ fr) * 16u;
  const uint32_t aE0 = ldsBase + (uint32_t)waveM * 8192u
                     + (uint32_t)r5 * 64u + slotA;       // buf0, j even
  const uint32_t aO0 = aE0 ^ 32u;                        // buf0, j odd
  const uint32_t aE1 = aE0 + LDS_BUF;
  const uint32_t aO1 = aO0 + LDS_BUF;
  const uint32_t bE0 = ldsBase + LDS_B_OFF + (uint32_t)waveN * 4096u
                     + (uint32_t)r5 * 64u + slotA;
  const uint32_t bO0 = bE0 ^ 32u;
  const uint32_t bE1 = bE0 + LDS_BUF;
  const uint32_t bO1 = bO0 + LDS_BUF;

  // Staging: thread t covers region rows srow (copy 1) and srow+16
  // (copy 2: +131072 global, +1024 LDS). chnk = slot ^ f(srow); copy 2
  // uses f(srow+16) = f(srow)^2 -> global addr (g^32).
  const uint32_t srow  = (uint32_t)wid * 32u + (uint32_t)(lane >> 2);
  const uint32_t slot  = (uint32_t)(tid & 3);
  const uint32_t chnk  = slot ^ ((((srow >> 1) ^ (srow >> 3))) & 3u);
  const uint32_t ldsSt = (uint32_t)wid * 2048u + (uint32_t)lane * 16u;
  const char* Ab = (const char*)xb;
  const char* Bb = (const char*)tern;

  floatx4 a0f[4], a1f[4], b0f[2], b1f[2];
  floatx16 acc[4][2];

#define DSR(DST, ADDR, IMM)                                                \
  asm volatile("ds_read_b128 %0, %1 offset:%c2"                            \
               : "=v"(DST) : "v"(ADDR), "i"(IMM))

#define IA4(DST, ADDR, KC2) do {                                           \
    DSR(DST[0], ADDR, (KC2) * 16384 + 0 * 2048);                           \
    DSR(DST[1], ADDR, (KC2) * 16384 + 1 * 2048);                           \
    DSR(DST[2], ADDR, (KC2) * 16384 + 2 * 2048);                           \
    DSR(DST[3], ADDR, (KC2) * 16384 + 3 * 2048);                           \
  } while (0)

#define IB2(DST, ADDR, KC2) do {                                           \
    DSR(DST[0], ADDR, (KC2) * 16384 + 0 * 2048);                           \
    DSR(DST[1], ADDR, (KC2) * 16384 + 1 * 2048);                           \
  } while (0)

#define STAGE_A(BUF, KH, KB) do {                                          \
    uint32_t g_ = stA + (KB) + (KH) * 64u;                                 \
    uint32_t l_ = (BUF) * LDS_BUF + (KH) * LDS_KC + ldsSt;                 \
    async_copy16(Ab + g_,                     lds + l_);                   \
    async_copy16(Ab + ((g_ ^ 32u) + 131072u), lds + l_ + 1024u);           \
  } while (0)

#define STAGE_B(BUF, KH, KB) do {                                          \
    uint32_t g_ = stB + (KB) + (KH) * 64u;                                 \
    uint32_t l_ = (BUF) * LDS_BUF + LDS_B_OFF + (KH) * LDS_KC + ldsSt;     \
    async_copy16(Bb + g_,                     lds + l_);                   \
    async_copy16(Bb + ((g_ ^ 32u) + 131072u), lds + l_ + 1024u);           \
  } while (0)

#define PHASE(AF, BF, ISSUE_STMT, STAGE_STMT) do {                         \
    asm volatile("s_waitcnt lgkmcnt(0)" ::: "memory");                     \
    asm volatile("s_waitcnt vmcnt(8)" ::: "memory");                       \
    __builtin_amdgcn_sched_barrier(0);                                     \
    ISSUE_STMT;                                                            \
    __builtin_amdgcn_sched_barrier(0);                                     \
    __builtin_amdgcn_s_setprio(1);                                         \
    _Pragma("unroll")                                                      \
    for (int m_ = 0; m_ < 4; ++m_)                                         \
      _Pragma("unroll")                                                    \
      for (int n_ = 0; n_ < 2; ++n_)                                       \
        acc[m_][n_] = __builtin_amdgcn_mfma_f32_32x32x16_bf16(             \
            __builtin_bit_cast(bf16x8, AF[m_]),                            \
            __builtin_bit_cast(bf16x8, BF[n_]),                            \
            acc[m_][n_], 0, 0, 0);                                         \
    __builtin_amdgcn_s_setprio(0);                                         \
    STAGE_STMT;                                                            \
    __builtin_amdgcn_s_barrier();                                          \
  } while (0)

#pragma unroll 1
  for (int t = 0; t < 2; ++t) {
    // Bijective XCD swizzle over 512 logical tiles; t=0/t=1 share bn.
    const uint32_t flat = b + (uint32_t)t * 256u;
    const uint32_t swz  = ((flat & 7u) << 6) | (flat >> 3);
    const uint32_t bm = (swz >> 4) * 256u;
    const uint32_t bn = (swz & 15u) * 256u;
    const uint32_t stA = (bm + srow) * (DIN * 2u) + chnk * 16u;
    const uint32_t stB = (bn + srow) * (DIN * 2u) + chnk * 16u;

#pragma unroll
    for (int m = 0; m < 4; ++m)
#pragma unroll
      for (int n = 0; n < 2; ++n)
        acc[m][n] = (floatx16)0.0f;

    // Tile-boundary drain before re-staging the same LDS regions.
    asm volatile("s_waitcnt lgkmcnt(0)" ::: "memory");
    asm volatile("s_waitcnt vmcnt(0)" ::: "memory");
    __builtin_amdgcn_s_barrier();

    // Prologue: 7 regions in steady-state stage order.
    STAGE_B(0, 0, 0u);    // b0.Bk0
    STAGE_A(0, 0, 0u);    // b0.Ak0
    STAGE_B(0, 1, 0u);    // b0.Bk1
    STAGE_A(0, 1, 0u);    // b0.Ak1
    STAGE_B(1, 0, 128u);  // b1.Bk0
    STAGE_A(1, 0, 128u);  // b1.Ak0
    STAGE_B(1, 1, 128u);  // b1.Bk1
    asm volatile("s_waitcnt vmcnt(8)" ::: "memory");   // b0.kc0 landed
    __builtin_amdgcn_s_barrier();
    // Prime bank for Ph1's MFMA: buf0 j0.
    IA4(a0f, aE0, 0);
    IB2(b0f, bE0, 0);

#pragma unroll 1
    for (int i = 0; i < 32; ++i) {
      const uint32_t kb1 = (uint32_t)(2 * i + 1) * 128u;
      const uint32_t kb2 = (uint32_t)((2 * i + 2) & 63) * 128u;  // wraps: valid mem, never read
      const uint32_t kb3 = (uint32_t)((2 * i + 3) & 63) * 128u;

      PHASE(a0f, b0f, { IA4(a1f, aO0, 0); IB2(b1f, bO0, 0); },
            STAGE_A(1, 1, kb1));                                   // Ph1: b0.j0
      PHASE(a1f, b1f, { IA4(a0f, aE0, 1); IB2(b0f, bE0, 1); },
            STAGE_B(0, 0, kb2));                                   // Ph2: b0.j1
      PHASE(a0f, b0f, { IA4(a1f, aO0, 1); IB2(b1f, bO0, 1); },
            STAGE_A(0, 0, kb2));                                   // Ph3: b0.j2
      PHASE(a1f, b1f, { IA4(a0f, aE1, 0); IB2(b0f, bE1, 0); },
            STAGE_B(0, 1, kb2));                                   // Ph4: b0.j3
      PHASE(a0f, b0f, { IA4(a1f, aO1, 0); IB2(b1f, bO1, 0); },
            STAGE_A(0, 1, kb2));                                   // Ph5: b1.j0
      PHASE(a1f, b1f, { IA4(a0f, aE1, 1); IB2(b0f, bE1, 1); },
            STAGE_B(1, 0, kb3));                                   // Ph6: b1.j1
      PHASE(a0f, b0f, { IA4(a1f, aO1, 1); IB2(b1f, bO1, 1); },
            STAGE_A(1, 0, kb3));                                   // Ph7: b1.j2
      PHASE(a1f, b1f, { IA4(a0f, aE0, 0); IB2(b0f, bE0, 0); },
            STAGE_B(1, 1, kb3));                                   // Ph8: b1.j3
    }

    // C/D layout (32x32x16): col = lane&31, row = (reg&3)+8*(reg>>2)+4*q.
    const int col0 = (int)bn + waveN * 64 + r5;
    const int row0 = (int)bm + waveM * 128 + q * 4;
    float* Cp = C + (size_t)row0 * DOUT + col0;
#pragma unroll
    for (int m = 0; m < 4; ++m)
#pragma unroll
      for (int n = 0; n < 2; ++n)
#pragma unroll
        for (int g = 0; g < 4; ++g)
#pragma unroll
          for (int e = 0; e < 4; ++e)
            Cp[(size_t)(m * 32 + g * 8 + e) * DOUT + n * 32] =
                acc[m][n][g * 4 + e];
  }

#undef DSR
#undef IA4
#undef IB2
#undef STAGE_A
#undef STAGE_B
#undef PHASE
}

extern "C" void kernel_launch(void* const* d_in, const int* in_sizes, int n_in,
                              void* d_out, int out_size, void* d_ws, size_t ws_size,
                              hipStream_t stream) {
  const float* x  = (const float*)d_in[0];   // [8192, 4096] fp32
  const float* wp = (const float*)d_in[1];   // [4096, 4096] fp32
  const float* wn = (const float*)d_in[2];   // [4096, 4096] fp32
  float* out = (float*)d_out;                // [8192, 4096] fp32

  unsigned short* xb   = (unsigned short*)d_ws;
  unsigned short* tern = xb + (size_t)TOKENS * DIN;

  // Cooperative launch: 256 blocks x 512 threads, 1 block/CU (128 KiB
  // LDS), all co-resident -> this_grid().sync() is valid.
  void* args[6] = {
      (void*)&x, (void*)&wp, (void*)&wn,
      (void*)&xb, (void*)&tern, (void*)&out,
  };
  (void)hipLaunchCooperativeKernel((const void*)fused_kernel,
                                   dim3(256), dim3(512), args, 0, stream);
}